// Round 3
// baseline (5027.945 us; speedup 1.0000x reference)
//
#include <hip/hip_runtime.h>

// DCGRU cell, MI355X gfx950.  N=4096, B=64, IN_DIM=2, UNITS=64, K=2, NSUP=2,
// M=5, IN_SZ=66.  Heavy: 8x GEMM Y(4096x4224)=S(4096x4096)@X, bf16 MFMA.
// R3: GEMM loads fragments DIRECT global->register (no LDS, no barriers),
// software-pipelined 1 K-iter ahead.  Rationale: LDS path was read-throughput
// bound (32KB/blk-iter at 8-way b128 aliasing ~= 512cy vs 77cy MFMA); intra-
// block reuse is only 2x, which L1 covers.  Projections are MFMA GEMMs over
// K=330 (pad 384) with k-pair-interleaved LDS staging of X.

typedef unsigned short u16;
typedef unsigned int u32;
typedef __attribute__((ext_vector_type(8))) short short8;   // bf16x8 MFMA frag
typedef __attribute__((ext_vector_type(4))) float floatx4;  // MFMA acc
typedef __attribute__((ext_vector_type(4))) u16 u16x4;

__device__ __forceinline__ u16 f2b(float f) {            // fp32 -> bf16 RNE
    u32 x = __float_as_uint(f);
    return (u16)((x + 0x7fffu + ((x >> 16) & 1u)) >> 16);
}
__device__ __forceinline__ float b2f(u16 u) {
    return __uint_as_float(((u32)u) << 16);
}

// ---------------------------------------------------------------- cvt fp32->bf16
__global__ void cvt_bf16_kernel(const float* __restrict__ src, u16* __restrict__ dst) {
    size_t i = ((size_t)blockIdx.x * 256 + threadIdx.x) * 4;
    floatx4 v = *(const floatx4*)&src[i];
    u16x4 p; p[0] = f2b(v[0]); p[1] = f2b(v[1]); p[2] = f2b(v[2]); p[3] = f2b(v[3]);
    *(u16x4*)&dst[i] = p;
}

// ------------------------------------------- x0T rows 0..127  (c=0,1 from inputs)
__global__ void build_x0_inputs(const float* __restrict__ inp, u16* __restrict__ x0T) {
    const int row = blockIdx.x;           // 0..127
    const int c = row >> 6, b = row & 63;
    const int t = threadIdx.x;
    const int n0 = t * 16;
    u16* dst = x0T + (size_t)row * 4096 + n0;
    #pragma unroll
    for (int g = 0; g < 4; ++g) {
        u16x4 pk;
        #pragma unroll
        for (int e = 0; e < 4; ++e) {
            const float* p = &inp[(size_t)b * 8192 + (size_t)(n0 + g * 4 + e) * 2];
            pk[e] = f2b(c ? p[1] : p[0]);
        }
        *(u16x4*)(dst + g * 4) = pk;
    }
}

// ----------------------------- x0T rows 128..4223 from state (hx):  transpose
__global__ void build_x0_state(const float* __restrict__ st, u16* __restrict__ x0T) {
    __shared__ float lds[64 * 68];
    const int t = threadIdx.x;
    const int n0 = blockIdx.x * 64, b = blockIdx.y;
    const float* src = st + (size_t)b * 262144 + (size_t)n0 * 64;
    #pragma unroll
    for (int r = 0; r < 4; ++r) {
        int i = r * 1024 + t * 4;
        floatx4 v = *(const floatx4*)&src[i];
        int nl = i >> 6, j = i & 63;
        *(floatx4*)&lds[nl * 68 + j] = v;
    }
    __syncthreads();
    const int j = t >> 2, q = t & 3;
    u16* dst = x0T + (size_t)((j + 2) * 64 + b) * 4096 + n0 + q * 16;
    #pragma unroll
    for (int g = 0; g < 4; ++g) {
        u16x4 pk;
        #pragma unroll
        for (int e = 0; e < 4; ++e) pk[e] = f2b(lds[(q * 16 + g * 4 + e) * 68 + j]);
        *(u16x4*)(dst + g * 4) = pk;
    }
}

// -------------------------------------------- W^T prep: WT[o][k] bf16, k pad 384
__global__ void wt_prep(const float* __restrict__ W, u16* __restrict__ WT, int O) {
    int idx = blockIdx.x * 256 + threadIdx.x;   // o*384 + k
    int o = idx / 384, k = idx - o * 384;
    if (o < O) WT[idx] = (k < 330) ? f2b(W[(size_t)k * O + o]) : (u16)0;
}

// --------------------------------------------------------------- bf16 MFMA GEMM
// C[m][col] = sum_k A[m][k]*XT[col][k]; store YT[col][m].  EPI: Y = 2*C - Z.
// Direct global->register fragment loads, register double-buffer, no LDS.
template <int EPI>
__global__ __launch_bounds__(256, 3) void gemm_kernel(
        const u16* __restrict__ A, const u16* __restrict__ B,
        u16* __restrict__ Y, const u16* __restrict__ Z) {
    const int t = threadIdx.x;
    const int lane = t & 63, wave = t >> 6;
    const int m16 = lane & 15, quad = lane >> 4;
    const int wr = wave >> 1, wc = wave & 1;
    const int rb = blockIdx.x, cb = blockIdx.y;

    const u16* aP[4];
    const u16* bP[4];
    #pragma unroll
    for (int i = 0; i < 4; ++i)
        aP[i] = A + (size_t)(rb * 128 + wr * 64 + i * 16 + m16) * 4096 + quad * 8;
    #pragma unroll
    for (int j = 0; j < 4; ++j)
        bP[j] = B + (size_t)(cb * 128 + wc * 64 + j * 16 + m16) * 4096 + quad * 8;

    floatx4 acc[4][4];
    #pragma unroll
    for (int i = 0; i < 4; ++i)
        #pragma unroll
        for (int j = 0; j < 4; ++j) acc[i][j] = (floatx4)0.f;

    short8 af0[4], bf0[4], af1[4], bf1[4];
    #pragma unroll
    for (int i = 0; i < 4; ++i) af0[i] = *(const short8*)aP[i];
    #pragma unroll
    for (int j = 0; j < 4; ++j) bf0[j] = *(const short8*)bP[j];

    // NOTE: final prefetch (kt+2==128) reads 64B past each row end -- stays
    // inside the workspace (all operand buffers are interior), values unused.
    for (int kt = 0; kt < 128; kt += 2) {
        const int o1 = (kt + 1) * 32, o2 = (kt + 2) * 32;
        #pragma unroll
        for (int i = 0; i < 4; ++i) af1[i] = *(const short8*)(aP[i] + o1);
        #pragma unroll
        for (int j = 0; j < 4; ++j) bf1[j] = *(const short8*)(bP[j] + o1);
        #pragma unroll
        for (int i = 0; i < 4; ++i)
            #pragma unroll
            for (int j = 0; j < 4; ++j)
                acc[i][j] = __builtin_amdgcn_mfma_f32_16x16x32_bf16(af0[i], bf0[j], acc[i][j], 0, 0, 0);
        #pragma unroll
        for (int i = 0; i < 4; ++i) af0[i] = *(const short8*)(aP[i] + o2);
        #pragma unroll
        for (int j = 0; j < 4; ++j) bf0[j] = *(const short8*)(bP[j] + o2);
        #pragma unroll
        for (int i = 0; i < 4; ++i)
            #pragma unroll
            for (int j = 0; j < 4; ++j)
                acc[i][j] = __builtin_amdgcn_mfma_f32_16x16x32_bf16(af1[i], bf1[j], acc[i][j], 0, 0, 0);
    }

    #pragma unroll
    for (int i = 0; i < 4; ++i) {
        const int row = rb * 128 + wr * 64 + i * 16 + quad * 4;
        #pragma unroll
        for (int j = 0; j < 4; ++j) {
            const int col = cb * 128 + wc * 64 + j * 16 + m16;
            const size_t off = (size_t)col * 4096 + row;
            floatx4 v = acc[i][j];
            if (EPI) {
                u16x4 z = *(const u16x4*)(Z + off);
                #pragma unroll
                for (int e = 0; e < 4; ++e) v[e] = 2.f * v[e] - b2f(z[e]);
            }
            u16x4 pk;
            #pragma unroll
            for (int e = 0; e < 4; ++e) pk[e] = f2b(v[e]);
            *(u16x4*)(Y + off) = pk;
        }
    }
}

// --------------------------------------------------------- proj helpers (X rows)
__device__ __forceinline__ const u16* xrow(int k, int b,
        const u16* x0, const u16* y1, const u16* y2, const u16* y3, const u16* y4) {
    int c = (int)((unsigned)k / 5u);
    int m = k - c * 5;
    if (c > 65) c = 65;                       // pad region: clamp in-bounds (W=0 there)
    const u16* base = (m == 0) ? x0 : (m == 1) ? y1 : (m == 2) ? y2 : (m == 3) ? y3 : y4;
    return base + (size_t)(c * 64 + b) * 4096;
}

__device__ __forceinline__ void ilv(uint4 a, uint4 b, u32* w) {
    // a = 8 bf16 of row k, b = 8 bf16 of row k+1 -> 8 words (k|k+1<<16) per bn
    const u32* ap = (const u32*)&a; const u32* bp = (const u32*)&b;
    #pragma unroll
    for (int i = 0; i < 4; ++i) {
        u32 x = ap[i], y = bp[i];
        w[2 * i]     = (x & 0xffffu) | (y << 16);
        w[2 * i + 1] = (x >> 16) | (y & 0xffff0000u);
    }
}

// ------------------------------------------------- proj fn: MFMA GEMM + gates
__global__ __launch_bounds__(256, 2) void proj_fn_kernel(
        const u16* __restrict__ x0T, const u16* __restrict__ y1T,
        const u16* __restrict__ y2T, const u16* __restrict__ y3T,
        const u16* __restrict__ y4T,
        const u16* __restrict__ WT, const float* __restrict__ bias,
        const float* __restrict__ hx,
        u16* __restrict__ u_t, u16* __restrict__ x0Tw) {
    __shared__ __align__(16) u32 Xs[32 * 132];   // [kp][bn] interleaved
    __shared__ __align__(16) u16 Ws[128 * 72];   // [o][k] pad 72
    const int t = threadIdx.x;
    const int lane = t & 63, wave = t >> 6;
    const int m16 = lane & 15, quad = lane >> 4;
    const int wr = wave >> 1, wc = wave & 1;
    const int n0 = blockIdx.x * 128, b = blockIdx.y;

    const int kp = t >> 3, sgx = t & 7;
    const int wrow = t >> 1, whalf = t & 1;

    floatx4 acc[4][4];
    #pragma unroll
    for (int i = 0; i < 4; ++i)
        #pragma unroll
        for (int j = 0; j < 4; ++j) acc[i][j] = (floatx4)0.f;

    for (int ki = 0; ki < 6; ++ki) {
        const int k0 = ki * 64;
        const u16* pa = xrow(k0 + 2 * kp,     b, x0T, y1T, y2T, y3T, y4T) + n0 + sgx * 16;
        const u16* pb = xrow(k0 + 2 * kp + 1, b, x0T, y1T, y2T, y3T, y4T) + n0 + sgx * 16;
        uint4 a0 = *(const uint4*)pa;
        uint4 a1 = *(const uint4*)(pa + 8);
        uint4 b0 = *(const uint4*)pb;
        uint4 b1 = *(const uint4*)(pb + 8);
        const u16* wsrc = WT + (size_t)wrow * 384 + k0 + whalf * 32;
        uint4 wv[4];
        #pragma unroll
        for (int q = 0; q < 4; ++q) wv[q] = *(const uint4*)(wsrc + q * 8);

        u32 w[16];
        ilv(a0, b0, w);
        ilv(a1, b1, w + 8);
        __syncthreads();
        u32* xdst = &Xs[kp * 132 + sgx * 16];
        #pragma unroll
        for (int q = 0; q < 4; ++q) *(uint4*)(xdst + q * 4) = *(uint4*)(w + q * 4);
        uint4* wdst = (uint4*)&Ws[wrow * 72 + whalf * 32];
        #pragma unroll
        for (int q = 0; q < 4; ++q) wdst[q] = wv[q];
        __syncthreads();

        #pragma unroll
        for (int ks = 0; ks < 2; ++ks) {
            short8 af[4], bf[4];
            #pragma unroll
            for (int i = 0; i < 4; ++i)
                af[i] = *(const short8*)&Ws[(wr * 64 + i * 16 + m16) * 72 + ks * 32 + quad * 8];
            #pragma unroll
            for (int j = 0; j < 4; ++j) {
                const u32* xp = &Xs[(ks * 16 + quad * 4) * 132 + wc * 64 + j * 16 + m16];
                union { uint4 u; short8 s; } fu;
                fu.u.x = xp[0]; fu.u.y = xp[132]; fu.u.z = xp[264]; fu.u.w = xp[396];
                bf[j] = fu.s;
            }
            #pragma unroll
            for (int i = 0; i < 4; ++i)
                #pragma unroll
                for (int j = 0; j < 4; ++j)
                    acc[i][j] = __builtin_amdgcn_mfma_f32_16x16x32_bf16(af[i], bf[j], acc[i][j], 0, 0, 0);
        }
    }
    #pragma unroll
    for (int i = 0; i < 4; ++i) {
        const int o0 = wr * 64 + i * 16 + quad * 4;
        floatx4 bz = *(const floatx4*)&bias[o0];
        #pragma unroll
        for (int j = 0; j < 4; ++j) {
            const int bnl = wc * 64 + j * 16 + m16;
            const size_t bn = (size_t)b * 4096 + n0 + bnl;
            floatx4 v = acc[i][j];
            float s[4];
            #pragma unroll
            for (int e = 0; e < 4; ++e) s[e] = 1.f / (1.f + __expf(-(v[e] + bz[e])));
            if (wr == 0) {
                floatx4 hv = *(const floatx4*)&hx[bn * 64 + o0];
                #pragma unroll
                for (int e = 0; e < 4; ++e)
                    x0Tw[(size_t)((o0 + e + 2) * 64 + b) * 4096 + (n0 + bnl)] = f2b(s[e] * hv[e]);
            } else {
                u16x4 pk;
                #pragma unroll
                for (int e = 0; e < 4; ++e) pk[e] = f2b(s[e]);
                *(u16x4*)&u_t[bn * 64 + (o0 - 64)] = pk;
            }
        }
    }
}

// --------------------------------------- proj g: MFMA GEMM + tanh + GRU output
__global__ __launch_bounds__(256, 2) void proj_g_kernel(
        const u16* __restrict__ x0T, const u16* __restrict__ y1T,
        const u16* __restrict__ y2T, const u16* __restrict__ y3T,
        const u16* __restrict__ y4T,
        const u16* __restrict__ WT, const float* __restrict__ bias,
        const float* __restrict__ hx, const u16* __restrict__ u_t,
        float* __restrict__ out) {
    __shared__ __align__(16) u32 Xs[32 * 132];
    __shared__ __align__(16) u16 Ws[64 * 72];
    const int t = threadIdx.x;
    const int lane = t & 63, wave = t >> 6;
    const int m16 = lane & 15, quad = lane >> 4;
    const int wr = wave >> 1, wc = wave & 1;
    const int n0 = blockIdx.x * 128, b = blockIdx.y;

    const int kp = t >> 3, sgx = t & 7;
    const int wrow = t >> 2, wq = t & 3;

    floatx4 acc[2][4];
    #pragma unroll
    for (int i = 0; i < 2; ++i)
        #pragma unroll
        for (int j = 0; j < 4; ++j) acc[i][j] = (floatx4)0.f;

    for (int ki = 0; ki < 6; ++ki) {
        const int k0 = ki * 64;
        const u16* pa = xrow(k0 + 2 * kp,     b, x0T, y1T, y2T, y3T, y4T) + n0 + sgx * 16;
        const u16* pb = xrow(k0 + 2 * kp + 1, b, x0T, y1T, y2T, y3T, y4T) + n0 + sgx * 16;
        uint4 a0 = *(const uint4*)pa;
        uint4 a1 = *(const uint4*)(pa + 8);
        uint4 b0 = *(const uint4*)pb;
        uint4 b1 = *(const uint4*)(pb + 8);
        const u16* wsrc = WT + (size_t)wrow * 384 + k0 + wq * 16;
        uint4 w0 = *(const uint4*)wsrc;
        uint4 w1 = *(const uint4*)(wsrc + 8);

        u32 w[16];
        ilv(a0, b0, w);
        ilv(a1, b1, w + 8);
        __syncthreads();
        u32* xdst = &Xs[kp * 132 + sgx * 16];
        #pragma unroll
        for (int q = 0; q < 4; ++q) *(uint4*)(xdst + q * 4) = *(uint4*)(w + q * 4);
        *(uint4*)&Ws[wrow * 72 + wq * 16] = w0;
        *(uint4*)&Ws[wrow * 72 + wq * 16 + 8] = w1;
        __syncthreads();

        #pragma unroll
        for (int ks = 0; ks < 2; ++ks) {
            short8 af[2], bf[4];
            #pragma unroll
            for (int i = 0; i < 2; ++i)
                af[i] = *(const short8*)&Ws[(wr * 32 + i * 16 + m16) * 72 + ks * 32 + quad * 8];
            #pragma unroll
            for (int j = 0; j < 4; ++j) {
                const u32* xp = &Xs[(ks * 16 + quad * 4) * 132 + wc * 64 + j * 16 + m16];
                union { uint4 u; short8 s; } fu;
                fu.u.x = xp[0]; fu.u.y = xp[132]; fu.u.z = xp[264]; fu.u.w = xp[396];
                bf[j] = fu.s;
            }
            #pragma unroll
            for (int i = 0; i < 2; ++i)
                #pragma unroll
                for (int j = 0; j < 4; ++j)
                    acc[i][j] = __builtin_amdgcn_mfma_f32_16x16x32_bf16(af[i], bf[j], acc[i][j], 0, 0, 0);
        }
    }
    #pragma unroll
    for (int i = 0; i < 2; ++i) {
        const int o0 = wr * 32 + i * 16 + quad * 4;
        floatx4 bz = *(const floatx4*)&bias[o0];
        #pragma unroll
        for (int j = 0; j < 4; ++j) {
            const int bnl = wc * 64 + j * 16 + m16;
            const size_t bn = (size_t)b * 4096 + n0 + bnl;
            floatx4 v = acc[i][j];
            u16x4 uu = *(const u16x4*)&u_t[bn * 64 + o0];
            floatx4 hv = *(const floatx4*)&hx[bn * 64 + o0];
            floatx4 ov;
            #pragma unroll
            for (int e = 0; e < 4; ++e) {
                float c = tanhf(v[e] + bz[e]);
                float u = b2f(uu[e]);
                ov[e] = u * hv[e] + (1.f - u) * c;
            }
            *(floatx4*)&out[bn * 64 + o0] = ov;
        }
    }
}

// --------------------------------------------------------------------- launch
extern "C" void kernel_launch(void* const* d_in, const int* in_sizes, int n_in,
                              void* d_out, int out_size, void* d_ws, size_t ws_size,
                              hipStream_t stream) {
    (void)in_sizes; (void)n_in; (void)out_size; (void)ws_size;
    const float* inputs   = (const float*)d_in[0];
    const float* hx       = (const float*)d_in[1];
    const float* supports = (const float*)d_in[2];
    const float* w_fn     = (const float*)d_in[3];
    const float* b_fn     = (const float*)d_in[4];
    const float* w_g      = (const float*)d_in[5];
    const float* b_g      = (const float*)d_in[6];
    float* out = (float*)d_out;

    const size_t NN = (size_t)4096 * 4096;
    const size_t XT = (size_t)4224 * 4096;
    u16* Sb  = (u16*)d_ws;                      // 67.1 MB
    u16* x0T = Sb + 2 * NN;                     // 34.6 MB each
    u16* y1T = x0T + XT;
    u16* y2T = y1T + XT;
    u16* y3T = y2T + XT;
    u16* y4T = y3T + XT;
    u16* u_t = y4T + XT;                        // [bn][o'] bf16
    u16* WT_fn = u_t + (size_t)262144 * 64;
    u16* WT_g  = WT_fn + 128 * 384;
    u16* S0b = Sb;
    u16* S1b = Sb + NN;

    const dim3 gg(32, 33);

    cvt_bf16_kernel<<<32768, 256, 0, stream>>>(supports, Sb);
    build_x0_inputs<<<128, 256, 0, stream>>>(inputs, x0T);
    build_x0_state<<<dim3(64, 64), 256, 0, stream>>>(hx, x0T);
    wt_prep<<<192, 256, 0, stream>>>(w_fn, WT_fn, 128);
    wt_prep<<<96, 256, 0, stream>>>(w_g, WT_g, 64);
    // gconv fn diffusion
    gemm_kernel<0><<<gg, 256, 0, stream>>>(S0b, x0T, y1T, nullptr);
    gemm_kernel<1><<<gg, 256, 0, stream>>>(S0b, y1T, y2T, x0T);
    gemm_kernel<0><<<gg, 256, 0, stream>>>(S1b, y1T, y3T, nullptr);
    gemm_kernel<1><<<gg, 256, 0, stream>>>(S1b, y3T, y4T, y1T);
    // r,u gates (MFMA): r*hx into x0T state rows, u into u_t
    proj_fn_kernel<<<dim3(32, 64), 256, 0, stream>>>(x0T, y1T, y2T, y3T, y4T,
                                                     WT_fn, b_fn, hx, u_t, x0T);
    // gconv g diffusion
    gemm_kernel<0><<<gg, 256, 0, stream>>>(S0b, x0T, y1T, nullptr);
    gemm_kernel<1><<<gg, 256, 0, stream>>>(S0b, y1T, y2T, x0T);
    gemm_kernel<0><<<gg, 256, 0, stream>>>(S1b, y1T, y3T, nullptr);
    gemm_kernel<1><<<gg, 256, 0, stream>>>(S1b, y3T, y4T, y1T);
    // c = tanh(...), out = u*hx + (1-u)*c
    proj_g_kernel<<<dim3(32, 64), 256, 0, stream>>>(x0T, y1T, y2T, y3T, y4T,
                                                    WT_g, b_g, hx, u_t, out);
}

// Round 4
// 2148.043 us; speedup vs baseline: 2.3407x; 2.3407x over previous
//
#include <hip/hip_runtime.h>

// DCGRU cell, MI355X gfx950.  N=4096, B=64, IN_DIM=2, UNITS=64, K=2, NSUP=2,
// M=5, IN_SZ=66.  Heavy: 8x GEMM Y(4096x4224)=S(4096x4096)@X, bf16 MFMA.
// R4: LDS staging via global_load_lds with DOUBLE-BUFFERED LDS and a single
// barrier per K-iter; prefetch of tile kt+1 is issued right after the barrier
// and drains (cheaply) at the NEXT barrier, so global latency overlaps the
// MFMA phase.  (R3's no-LDS direct-register variant was latency-bound: 595us,
// MfmaUtil 9.5%.)  Projections are MFMA GEMMs over K=330 (pad 384).

typedef unsigned short u16;
typedef unsigned int u32;
typedef __attribute__((ext_vector_type(8))) short short8;   // bf16x8 MFMA frag
typedef __attribute__((ext_vector_type(4))) float floatx4;  // MFMA acc
typedef __attribute__((ext_vector_type(4))) u16 u16x4;

__device__ __forceinline__ u16 f2b(float f) {            // fp32 -> bf16 RNE
    u32 x = __float_as_uint(f);
    return (u16)((x + 0x7fffu + ((x >> 16) & 1u)) >> 16);
}
__device__ __forceinline__ float b2f(u16 u) {
    return __uint_as_float(((u32)u) << 16);
}

// async global->LDS, 16B per lane; LDS dest = wave-uniform base + lane*16
#define GLL16(g, l) __builtin_amdgcn_global_load_lds( \
    (const __attribute__((address_space(1))) void*)(g), \
    (__attribute__((address_space(3))) void*)(l), 16, 0, 0)

// ---------------------------------------------------------------- cvt fp32->bf16
__global__ void cvt_bf16_kernel(const float* __restrict__ src, u16* __restrict__ dst) {
    size_t i = ((size_t)blockIdx.x * 256 + threadIdx.x) * 4;
    floatx4 v = *(const floatx4*)&src[i];
    u16x4 p; p[0] = f2b(v[0]); p[1] = f2b(v[1]); p[2] = f2b(v[2]); p[3] = f2b(v[3]);
    *(u16x4*)&dst[i] = p;
}

// ------------------------------------------- x0T rows 0..127  (c=0,1 from inputs)
__global__ void build_x0_inputs(const float* __restrict__ inp, u16* __restrict__ x0T) {
    const int row = blockIdx.x;           // 0..127
    const int c = row >> 6, b = row & 63;
    const int t = threadIdx.x;
    const int n0 = t * 16;
    u16* dst = x0T + (size_t)row * 4096 + n0;
    #pragma unroll
    for (int g = 0; g < 4; ++g) {
        u16x4 pk;
        #pragma unroll
        for (int e = 0; e < 4; ++e) {
            const float* p = &inp[(size_t)b * 8192 + (size_t)(n0 + g * 4 + e) * 2];
            pk[e] = f2b(c ? p[1] : p[0]);
        }
        *(u16x4*)(dst + g * 4) = pk;
    }
}

// ----------------------------- x0T rows 128..4223 from state (hx):  transpose
__global__ void build_x0_state(const float* __restrict__ st, u16* __restrict__ x0T) {
    __shared__ float lds[64 * 68];
    const int t = threadIdx.x;
    const int n0 = blockIdx.x * 64, b = blockIdx.y;
    const float* src = st + (size_t)b * 262144 + (size_t)n0 * 64;
    #pragma unroll
    for (int r = 0; r < 4; ++r) {
        int i = r * 1024 + t * 4;
        floatx4 v = *(const floatx4*)&src[i];
        int nl = i >> 6, j = i & 63;
        *(floatx4*)&lds[nl * 68 + j] = v;
    }
    __syncthreads();
    const int j = t >> 2, q = t & 3;
    u16* dst = x0T + (size_t)((j + 2) * 64 + b) * 4096 + n0 + q * 16;
    #pragma unroll
    for (int g = 0; g < 4; ++g) {
        u16x4 pk;
        #pragma unroll
        for (int e = 0; e < 4; ++e) pk[e] = f2b(lds[(q * 16 + g * 4 + e) * 68 + j]);
        *(u16x4*)(dst + g * 4) = pk;
    }
}

// -------------------------------------------- W^T prep: WT[o][k] bf16, k pad 384
__global__ void wt_prep(const float* __restrict__ W, u16* __restrict__ WT, int O) {
    int idx = blockIdx.x * 256 + threadIdx.x;   // o*384 + k
    int o = idx / 384, k = idx - o * 384;
    if (o < O) WT[idx] = (k < 330) ? f2b(W[(size_t)k * O + o]) : (u16)0;
}

// --------------------------------------------------------------- bf16 MFMA GEMM
// C[m][col] = sum_k A[m][k]*XT[col][k]; store YT[col][m].  EPI: Y = 2*C - Z.
// Double-buffered LDS; one barrier per K-iter; prefetch overlaps MFMA.
template <int EPI>
__global__ __launch_bounds__(256, 2) void gemm_kernel(
        const u16* __restrict__ A, const u16* __restrict__ B,
        u16* __restrict__ Y, const u16* __restrict__ Z) {
    __shared__ __align__(16) u16 As[2][128 * 32];
    __shared__ __align__(16) u16 Bs[2][128 * 32];
    const int t = threadIdx.x;
    const int lane = t & 63, wave = t >> 6;
    const int m16 = lane & 15, quad = lane >> 4;
    const int wr = wave >> 1, wc = wave & 1;
    const int rb = blockIdx.x, cb = blockIdx.y;

    // staging: wave w covers rows w*32..w*32+31; one instr = 16 rows (64 lanes x 16B)
    const int r0 = wave * 32 + (lane >> 2);
    const int sg = lane & 3;
    const u16* aG = A + (size_t)(rb * 128 + r0) * 4096 + sg * 8;
    const u16* bG = B + (size_t)(cb * 128 + r0) * 4096 + sg * 8;
    const int lw = wave * 1024;   // wave-uniform LDS base (u16 units)

    floatx4 acc[4][4];
    #pragma unroll
    for (int i = 0; i < 4; ++i)
        #pragma unroll
        for (int j = 0; j < 4; ++j) acc[i][j] = (floatx4)0.f;

    // prologue: stage tile 0 into buffer 0
    GLL16(aG, As[0] + lw);
    GLL16(aG + (size_t)16 * 4096, As[0] + lw + 512);
    GLL16(bG, Bs[0] + lw);
    GLL16(bG + (size_t)16 * 4096, Bs[0] + lw + 512);

    for (int kt = 0; kt < 128; ++kt) {
        __syncthreads();  // drains (old) GLLs into buf[cur]; rendezvous
        const int cur = kt & 1, nxt = cur ^ 1;
        if (kt < 127) {   // prefetch tile kt+1 into the other buffer
            const int off = (kt + 1) * 32;
            GLL16(aG + off, As[nxt] + lw);
            GLL16(aG + off + (size_t)16 * 4096, As[nxt] + lw + 512);
            GLL16(bG + off, Bs[nxt] + lw);
            GLL16(bG + off + (size_t)16 * 4096, Bs[nxt] + lw + 512);
        }
        short8 af[4], bf[4];
        #pragma unroll
        for (int i = 0; i < 4; ++i)
            af[i] = *(const short8*)&As[cur][(wr * 64 + i * 16 + m16) * 32 + quad * 8];
        #pragma unroll
        for (int j = 0; j < 4; ++j)
            bf[j] = *(const short8*)&Bs[cur][(wc * 64 + j * 16 + m16) * 32 + quad * 8];
        #pragma unroll
        for (int i = 0; i < 4; ++i)
            #pragma unroll
            for (int j = 0; j < 4; ++j)
                acc[i][j] = __builtin_amdgcn_mfma_f32_16x16x32_bf16(af[i], bf[j], acc[i][j], 0, 0, 0);
    }

    #pragma unroll
    for (int i = 0; i < 4; ++i) {
        const int row = rb * 128 + wr * 64 + i * 16 + quad * 4;
        #pragma unroll
        for (int j = 0; j < 4; ++j) {
            const int col = cb * 128 + wc * 64 + j * 16 + m16;
            const size_t off = (size_t)col * 4096 + row;
            floatx4 v = acc[i][j];
            if (EPI) {
                u16x4 z = *(const u16x4*)(Z + off);
                #pragma unroll
                for (int e = 0; e < 4; ++e) v[e] = 2.f * v[e] - b2f(z[e]);
            }
            u16x4 pk;
            #pragma unroll
            for (int e = 0; e < 4; ++e) pk[e] = f2b(v[e]);
            *(u16x4*)(Y + off) = pk;
        }
    }
}

// --------------------------------------------------------- proj helpers (X rows)
__device__ __forceinline__ const u16* xrow(int k, int b,
        const u16* x0, const u16* y1, const u16* y2, const u16* y3, const u16* y4) {
    int c = (int)((unsigned)k / 5u);
    int m = k - c * 5;
    if (c > 65) c = 65;                       // pad region: clamp in-bounds (W=0 there)
    const u16* base = (m == 0) ? x0 : (m == 1) ? y1 : (m == 2) ? y2 : (m == 3) ? y3 : y4;
    return base + (size_t)(c * 64 + b) * 4096;
}

__device__ __forceinline__ void ilv(uint4 a, uint4 b, u32* w) {
    // a = 8 bf16 of row k, b = 8 bf16 of row k+1 -> 8 words (k|k+1<<16) per bn
    const u32* ap = (const u32*)&a; const u32* bp = (const u32*)&b;
    #pragma unroll
    for (int i = 0; i < 4; ++i) {
        u32 x = ap[i], y = bp[i];
        w[2 * i]     = (x & 0xffffu) | (y << 16);
        w[2 * i + 1] = (x >> 16) | (y & 0xffff0000u);
    }
}

// ------------------------------------------------- proj fn: MFMA GEMM + gates
__global__ __launch_bounds__(256, 2) void proj_fn_kernel(
        const u16* __restrict__ x0T, const u16* __restrict__ y1T,
        const u16* __restrict__ y2T, const u16* __restrict__ y3T,
        const u16* __restrict__ y4T,
        const u16* __restrict__ WT, const float* __restrict__ bias,
        const float* __restrict__ hx,
        u16* __restrict__ u_t, u16* __restrict__ x0Tw) {
    __shared__ __align__(16) u32 Xs[32 * 132];   // [kp][bn] interleaved
    __shared__ __align__(16) u16 Ws[128 * 72];   // [o][k] pad 72
    const int t = threadIdx.x;
    const int lane = t & 63, wave = t >> 6;
    const int m16 = lane & 15, quad = lane >> 4;
    const int wr = wave >> 1, wc = wave & 1;
    const int n0 = blockIdx.x * 128, b = blockIdx.y;

    const int kp = t >> 3, sgx = t & 7;
    const int wrow = t >> 1, whalf = t & 1;

    floatx4 acc[4][4];
    #pragma unroll
    for (int i = 0; i < 4; ++i)
        #pragma unroll
        for (int j = 0; j < 4; ++j) acc[i][j] = (floatx4)0.f;

    for (int ki = 0; ki < 6; ++ki) {
        const int k0 = ki * 64;
        const u16* pa = xrow(k0 + 2 * kp,     b, x0T, y1T, y2T, y3T, y4T) + n0 + sgx * 16;
        const u16* pb = xrow(k0 + 2 * kp + 1, b, x0T, y1T, y2T, y3T, y4T) + n0 + sgx * 16;
        uint4 a0 = *(const uint4*)pa;
        uint4 a1 = *(const uint4*)(pa + 8);
        uint4 b0 = *(const uint4*)pb;
        uint4 b1 = *(const uint4*)(pb + 8);
        const u16* wsrc = WT + (size_t)wrow * 384 + k0 + whalf * 32;
        uint4 wv[4];
        #pragma unroll
        for (int q = 0; q < 4; ++q) wv[q] = *(const uint4*)(wsrc + q * 8);

        u32 w[16];
        ilv(a0, b0, w);
        ilv(a1, b1, w + 8);
        __syncthreads();
        u32* xdst = &Xs[kp * 132 + sgx * 16];
        #pragma unroll
        for (int q = 0; q < 4; ++q) *(uint4*)(xdst + q * 4) = *(uint4*)(w + q * 4);
        uint4* wdst = (uint4*)&Ws[wrow * 72 + whalf * 32];
        #pragma unroll
        for (int q = 0; q < 4; ++q) wdst[q] = wv[q];
        __syncthreads();

        #pragma unroll
        for (int ks = 0; ks < 2; ++ks) {
            short8 af[4], bf[4];
            #pragma unroll
            for (int i = 0; i < 4; ++i)
                af[i] = *(const short8*)&Ws[(wr * 64 + i * 16 + m16) * 72 + ks * 32 + quad * 8];
            #pragma unroll
            for (int j = 0; j < 4; ++j) {
                const u32* xp = &Xs[(ks * 16 + quad * 4) * 132 + wc * 64 + j * 16 + m16];
                union { uint4 u; short8 s; } fu;
                fu.u.x = xp[0]; fu.u.y = xp[132]; fu.u.z = xp[264]; fu.u.w = xp[396];
                bf[j] = fu.s;
            }
            #pragma unroll
            for (int i = 0; i < 4; ++i)
                #pragma unroll
                for (int j = 0; j < 4; ++j)
                    acc[i][j] = __builtin_amdgcn_mfma_f32_16x16x32_bf16(af[i], bf[j], acc[i][j], 0, 0, 0);
        }
    }
    #pragma unroll
    for (int i = 0; i < 4; ++i) {
        const int o0 = wr * 64 + i * 16 + quad * 4;
        floatx4 bz = *(const floatx4*)&bias[o0];
        #pragma unroll
        for (int j = 0; j < 4; ++j) {
            const int bnl = wc * 64 + j * 16 + m16;
            const size_t bn = (size_t)b * 4096 + n0 + bnl;
            floatx4 v = acc[i][j];
            float s[4];
            #pragma unroll
            for (int e = 0; e < 4; ++e) s[e] = 1.f / (1.f + __expf(-(v[e] + bz[e])));
            if (wr == 0) {
                floatx4 hv = *(const floatx4*)&hx[bn * 64 + o0];
                #pragma unroll
                for (int e = 0; e < 4; ++e)
                    x0Tw[(size_t)((o0 + e + 2) * 64 + b) * 4096 + (n0 + bnl)] = f2b(s[e] * hv[e]);
            } else {
                u16x4 pk;
                #pragma unroll
                for (int e = 0; e < 4; ++e) pk[e] = f2b(s[e]);
                *(u16x4*)&u_t[bn * 64 + (o0 - 64)] = pk;
            }
        }
    }
}

// --------------------------------------- proj g: MFMA GEMM + tanh + GRU output
__global__ __launch_bounds__(256, 2) void proj_g_kernel(
        const u16* __restrict__ x0T, const u16* __restrict__ y1T,
        const u16* __restrict__ y2T, const u16* __restrict__ y3T,
        const u16* __restrict__ y4T,
        const u16* __restrict__ WT, const float* __restrict__ bias,
        const float* __restrict__ hx, const u16* __restrict__ u_t,
        float* __restrict__ out) {
    __shared__ __align__(16) u32 Xs[32 * 132];
    __shared__ __align__(16) u16 Ws[64 * 72];
    const int t = threadIdx.x;
    const int lane = t & 63, wave = t >> 6;
    const int m16 = lane & 15, quad = lane >> 4;
    const int wr = wave >> 1, wc = wave & 1;
    const int n0 = blockIdx.x * 128, b = blockIdx.y;

    const int kp = t >> 3, sgx = t & 7;
    const int wrow = t >> 2, wq = t & 3;

    floatx4 acc[2][4];
    #pragma unroll
    for (int i = 0; i < 2; ++i)
        #pragma unroll
        for (int j = 0; j < 4; ++j) acc[i][j] = (floatx4)0.f;

    for (int ki = 0; ki < 6; ++ki) {
        const int k0 = ki * 64;
        const u16* pa = xrow(k0 + 2 * kp,     b, x0T, y1T, y2T, y3T, y4T) + n0 + sgx * 16;
        const u16* pb = xrow(k0 + 2 * kp + 1, b, x0T, y1T, y2T, y3T, y4T) + n0 + sgx * 16;
        uint4 a0 = *(const uint4*)pa;
        uint4 a1 = *(const uint4*)(pa + 8);
        uint4 b0 = *(const uint4*)pb;
        uint4 b1 = *(const uint4*)(pb + 8);
        const u16* wsrc = WT + (size_t)wrow * 384 + k0 + wq * 16;
        uint4 w0 = *(const uint4*)wsrc;
        uint4 w1 = *(const uint4*)(wsrc + 8);

        u32 w[16];
        ilv(a0, b0, w);
        ilv(a1, b1, w + 8);
        __syncthreads();
        u32* xdst = &Xs[kp * 132 + sgx * 16];
        #pragma unroll
        for (int q = 0; q < 4; ++q) *(uint4*)(xdst + q * 4) = *(uint4*)(w + q * 4);
        *(uint4*)&Ws[wrow * 72 + wq * 16] = w0;
        *(uint4*)&Ws[wrow * 72 + wq * 16 + 8] = w1;
        __syncthreads();

        #pragma unroll
        for (int ks = 0; ks < 2; ++ks) {
            short8 af[2], bf[4];
            #pragma unroll
            for (int i = 0; i < 2; ++i)
                af[i] = *(const short8*)&Ws[(wr * 32 + i * 16 + m16) * 72 + ks * 32 + quad * 8];
            #pragma unroll
            for (int j = 0; j < 4; ++j) {
                const u32* xp = &Xs[(ks * 16 + quad * 4) * 132 + wc * 64 + j * 16 + m16];
                union { uint4 u; short8 s; } fu;
                fu.u.x = xp[0]; fu.u.y = xp[132]; fu.u.z = xp[264]; fu.u.w = xp[396];
                bf[j] = fu.s;
            }
            #pragma unroll
            for (int i = 0; i < 2; ++i)
                #pragma unroll
                for (int j = 0; j < 4; ++j)
                    acc[i][j] = __builtin_amdgcn_mfma_f32_16x16x32_bf16(af[i], bf[j], acc[i][j], 0, 0, 0);
        }
    }
    #pragma unroll
    for (int i = 0; i < 2; ++i) {
        const int o0 = wr * 32 + i * 16 + quad * 4;
        floatx4 bz = *(const floatx4*)&bias[o0];
        #pragma unroll
        for (int j = 0; j < 4; ++j) {
            const int bnl = wc * 64 + j * 16 + m16;
            const size_t bn = (size_t)b * 4096 + n0 + bnl;
            floatx4 v = acc[i][j];
            u16x4 uu = *(const u16x4*)&u_t[bn * 64 + o0];
            floatx4 hv = *(const floatx4*)&hx[bn * 64 + o0];
            floatx4 ov;
            #pragma unroll
            for (int e = 0; e < 4; ++e) {
                float c = tanhf(v[e] + bz[e]);
                float u = b2f(uu[e]);
                ov[e] = u * hv[e] + (1.f - u) * c;
            }
            *(floatx4*)&out[bn * 64 + o0] = ov;
        }
    }
}

// --------------------------------------------------------------------- launch
extern "C" void kernel_launch(void* const* d_in, const int* in_sizes, int n_in,
                              void* d_out, int out_size, void* d_ws, size_t ws_size,
                              hipStream_t stream) {
    (void)in_sizes; (void)n_in; (void)out_size; (void)ws_size;
    const float* inputs   = (const float*)d_in[0];
    const float* hx       = (const float*)d_in[1];
    const float* supports = (const float*)d_in[2];
    const float* w_fn     = (const float*)d_in[3];
    const float* b_fn     = (const float*)d_in[4];
    const float* w_g      = (const float*)d_in[5];
    const float* b_g      = (const float*)d_in[6];
    float* out = (float*)d_out;

    const size_t NN = (size_t)4096 * 4096;
    const size_t XT = (size_t)4224 * 4096;
    u16* Sb  = (u16*)d_ws;                      // 67.1 MB
    u16* x0T = Sb + 2 * NN;                     // 34.6 MB each
    u16* y1T = x0T + XT;
    u16* y2T = y1T + XT;
    u16* y3T = y2T + XT;
    u16* y4T = y3T + XT;
    u16* u_t = y4T + XT;                        // [bn][o'] bf16
    u16* WT_fn = u_t + (size_t)262144 * 64;
    u16* WT_g  = WT_fn + 128 * 384;
    u16* S0b = Sb;
    u16* S1b = Sb + NN;

    const dim3 gg(32, 33);

    cvt_bf16_kernel<<<32768, 256, 0, stream>>>(supports, Sb);
    build_x0_inputs<<<128, 256, 0, stream>>>(inputs, x0T);
    build_x0_state<<<dim3(64, 64), 256, 0, stream>>>(hx, x0T);
    wt_prep<<<192, 256, 0, stream>>>(w_fn, WT_fn, 128);
    wt_prep<<<96, 256, 0, stream>>>(w_g, WT_g, 64);
    // gconv fn diffusion
    gemm_kernel<0><<<gg, 256, 0, stream>>>(S0b, x0T, y1T, nullptr);
    gemm_kernel<1><<<gg, 256, 0, stream>>>(S0b, y1T, y2T, x0T);
    gemm_kernel<0><<<gg, 256, 0, stream>>>(S1b, y1T, y3T, nullptr);
    gemm_kernel<1><<<gg, 256, 0, stream>>>(S1b, y3T, y4T, y1T);
    // r,u gates (MFMA): r*hx into x0T state rows, u into u_t
    proj_fn_kernel<<<dim3(32, 64), 256, 0, stream>>>(x0T, y1T, y2T, y3T, y4T,
                                                     WT_fn, b_fn, hx, u_t, x0T);
    // gconv g diffusion
    gemm_kernel<0><<<gg, 256, 0, stream>>>(S0b, x0T, y1T, nullptr);
    gemm_kernel<1><<<gg, 256, 0, stream>>>(S0b, y1T, y2T, x0T);
    gemm_kernel<0><<<gg, 256, 0, stream>>>(S1b, y1T, y3T, nullptr);
    gemm_kernel<1><<<gg, 256, 0, stream>>>(S1b, y3T, y4T, y1T);
    // c = tanh(...), out = u*hx + (1-u)*c
    proj_g_kernel<<<dim3(32, 64), 256, 0, stream>>>(x0T, y1T, y2T, y3T, y4T,
                                                    WT_g, b_g, hx, u_t, out);
}